// Round 11
// baseline (239.250 us; speedup 1.0000x reference)
//
#include <hip/hip_runtime.h>
#include <math.h>

#define NU_F 0.0031830988618379067f

typedef _Float16 f16x8 __attribute__((ext_vector_type(8)));
typedef float    f32x4 __attribute__((ext_vector_type(4)));

// tanh(z) = 1 - 2/(exp2(z*2log2e)+1); 5 VALU (2 transcendental)
__device__ __forceinline__ float fast_tanh(float z) {
    float e = __builtin_amdgcn_exp2f(2.885390082f * z);
    float r = __builtin_amdgcn_rcpf(e + 1.0f);
    return fmaf(-2.0f, r, 1.0f);
}

// pack two f32 -> f16x2 in one u32 (v_cvt_pkrtz_f32_f16), low16 = a
__device__ __forceinline__ unsigned pkf16(float a, float b) {
    auto v = __builtin_amdgcn_cvt_pkrtz(a, b);   // __fp16 ext_vector(2)
    return __builtin_bit_cast(unsigned, v);
}

// ---------------------------------------------------------------------------
// Prep: W_hid fp32 [7][128(k)][128(c)] -> single f16 (RNE) B-fragments,
// fragment-major (each wave-load = one coalesced 1 KiB block):
//   fid = (l*8 + nt)*4 + ks ; element = fid*512 + lane*8 + jj
//   k = ks*32 + q*8 + jj, lane = q*16 + nn
//   channel-QUAD map (round-5 proven): nt = ((c>>6)<<2)|(c&3),
//   nn = (c>>2)&15  ->  real c = wv*64 + nn*4 + j   (wave wv: nt = wv*4+j)
// ---------------------------------------------------------------------------
__global__ void prep_wfrag(const float* __restrict__ Whid, _Float16* __restrict__ wcf)
{
    int t = blockIdx.x * 256 + threadIdx.x;   // 0 .. 114687
    const int l = t >> 14;
    const int r = t & 16383;
    const int k = r >> 7;
    const int c = r & 127;
    const _Float16 hi = (_Float16)Whid[t];
    const int ks = k >> 5, q = (k >> 3) & 3, jj = k & 7;
    const int nt = ((c >> 6) << 2) | (c & 3);
    const int nn = (c >> 2) & 15;
    const int lane = q * 16 + nn;
    wcf[((l * 8 + nt) * 4 + ks) * 512 + lane * 8 + jj] = hi;
}

#define HR 68
#define MFMA(A, B, C) __builtin_amdgcn_mfma_f32_16x16x32_f16((A), (B), (C), 0, 0, 0)

// ---------------------------------------------------------------------------
// Fused kernel, 128 thr = 2 waves; wave wv covers N-tiles wv*4..wv*4+3
// (channels wv*64 + nn*4 + j). Blocks 0..8191: 16 deriv pts (M rows =
// s*16+p, jet states v,vx,vt,vxx). Blocks 8192..8319: 64 value pts.
// H: SINGLE f16 buffer (u32-packed channel pairs), 64 x 68 dwords
// (~18.6 KB total LDS -> 8 blocks/CU = 16 waves/CU). Two barriers/layer.
// Each wave's 4 A-frags amortize over 4 N-tiles (A-reads halved vs 2-nt);
// epilogue writes are uint2/b64 (channel-quad per lane).
// __launch_bounds__(128,4): 128-reg cap (acc 64 + A 16 + B 16 + misc).
// ---------------------------------------------------------------------------
__global__ __launch_bounds__(128, 4)
void pinn_fused(const float* __restrict__ xf,
                const float* __restrict__ x0,  const float* __restrict__ xbl,
                const float* __restrict__ xbr,
                const float* __restrict__ Win,  const float* __restrict__ bin,
                const float* __restrict__ bhid,
                const float* __restrict__ Wout, const float* __restrict__ bout,
                const _Float16* __restrict__ wcf,
                float* __restrict__ out)
{
    __shared__ unsigned Hh[64 * HR];
    __shared__ float xpt[128];
    __shared__ float pbuf[128];
    __shared__ float dots[64];

    const int tid  = threadIdx.x;
    const int lane = tid & 63;
    const int wv   = tid >> 6;         // wave 0/1 -> N-tiles wv*4..wv*4+3
    const int lm   = lane & 15;
    const int lq   = lane >> 4;
    const int blk  = blockIdx.x;
    const bool isv = (blk >= 8192);

    if (!isv) {
        if (tid < 32) xpt[tid] = xf[blk * 32 + tid];
    } else {
        const int vb = blk - 8192;
        const float* src = (vb < 64) ? (x0 + vb * 128)
                         : (vb < 96) ? (xbl + (vb - 64) * 128)
                                     : (xbr + (vb - 96) * 128);
        xpt[tid] = src[tid];
    }
    __syncthreads();

    // ---- input layer: thread owns channel pair c0=2*(tid&63) ----
    const int cp = tid & 63;
    {
        const float2 w01 = *(const float2*)&Win[cp * 2];
        const float2 w11 = *(const float2*)&Win[128 + cp * 2];
        const float2 bb  = *(const float2*)&bin[cp * 2];
        if (!isv) {
            const int p0 = (tid >> 6) * 8;
            #pragma unroll
            for (int i = 0; i < 8; ++i) {
                const int p = p0 + i;
                const float x = xpt[2 * p], tt = xpt[2 * p + 1];
                const float za = fmaf(x, w01.x, fmaf(tt, w11.x, bb.x));
                const float zb = fmaf(x, w01.y, fmaf(tt, w11.y, bb.y));
                const float ya = fast_tanh(za), yb = fast_tanh(zb);
                const float da = 1.f - ya * ya, db = 1.f - yb * yb;
                Hh[(0 * 16 + p) * HR + cp] = pkf16(ya, yb);
                Hh[(1 * 16 + p) * HR + cp] = pkf16(da * w01.x, db * w01.y);
                Hh[(2 * 16 + p) * HR + cp] = pkf16(da * w11.x, db * w11.y);
                Hh[(3 * 16 + p) * HR + cp] =
                    pkf16(-2.f * ya * da * w01.x * w01.x,
                          -2.f * yb * db * w01.y * w01.y);
            }
        } else {
            const int p0 = (tid >> 6) * 32;
            #pragma unroll
            for (int i = 0; i < 32; ++i) {
                const int p = p0 + i;
                const float x = xpt[2 * p], tt = xpt[2 * p + 1];
                const float za = fmaf(x, w01.x, fmaf(tt, w11.x, bb.x));
                const float zb = fmaf(x, w01.y, fmaf(tt, w11.y, bb.y));
                Hh[p * HR + cp] = pkf16(fast_tanh(za), fast_tanh(zb));
            }
        }
    }
    __syncthreads();

    // B-fragment pointers: 4 N-tiles per wave, coalesced 1 KiB fragments.
    const _Float16* pb0 = wcf + (wv * 4 + 0) * 2048 + lane * 8;
    const _Float16* pb1 = wcf + (wv * 4 + 1) * 2048 + lane * 8;
    const _Float16* pb2 = wcf + (wv * 4 + 2) * 2048 + lane * 8;
    const _Float16* pb3 = wcf + (wv * 4 + 3) * 2048 + lane * 8;
    const int wc = wv * 32 + lm * 2;   // epilogue dword column (chan quad)

    if (!isv) {
        // ================= derivative path =================
        for (int l = 0; l < 7; ++l) {
            f32x4 acc[4][4];   // [state][nt j]
            #pragma unroll
            for (int s = 0; s < 4; ++s)
                #pragma unroll
                for (int j = 0; j < 4; ++j) acc[s][j] = (f32x4){0.f, 0.f, 0.f, 0.f};

            #pragma unroll
            for (int ks = 0; ks < 4; ++ks) {
                const int ro = ks * 16 + lq * 4;
                const f16x8 ah0 = *(const f16x8*)&Hh[(0 * 16 + lm) * HR + ro];
                const f16x8 ah1 = *(const f16x8*)&Hh[(1 * 16 + lm) * HR + ro];
                const f16x8 ah2 = *(const f16x8*)&Hh[(2 * 16 + lm) * HR + ro];
                const f16x8 ah3 = *(const f16x8*)&Hh[(3 * 16 + lm) * HR + ro];
                const f16x8 b0 = *(const f16x8*)(pb0 + ks * 512);
                const f16x8 b1 = *(const f16x8*)(pb1 + ks * 512);
                const f16x8 b2 = *(const f16x8*)(pb2 + ks * 512);
                const f16x8 b3 = *(const f16x8*)(pb3 + ks * 512);
                acc[0][0] = MFMA(ah0, b0, acc[0][0]);
                acc[1][0] = MFMA(ah1, b0, acc[1][0]);
                acc[2][0] = MFMA(ah2, b0, acc[2][0]);
                acc[3][0] = MFMA(ah3, b0, acc[3][0]);
                acc[0][1] = MFMA(ah0, b1, acc[0][1]);
                acc[1][1] = MFMA(ah1, b1, acc[1][1]);
                acc[2][1] = MFMA(ah2, b1, acc[2][1]);
                acc[3][1] = MFMA(ah3, b1, acc[3][1]);
                acc[0][2] = MFMA(ah0, b2, acc[0][2]);
                acc[1][2] = MFMA(ah1, b2, acc[1][2]);
                acc[2][2] = MFMA(ah2, b2, acc[2][2]);
                acc[3][2] = MFMA(ah3, b2, acc[3][2]);
                acc[0][3] = MFMA(ah0, b3, acc[0][3]);
                acc[1][3] = MFMA(ah1, b3, acc[1][3]);
                acc[2][3] = MFMA(ah2, b3, acc[2][3]);
                acc[3][3] = MFMA(ah3, b3, acc[3][3]);
            }
            __syncthreads();   // K-loop reads done before in-place overwrite

            float bb[4];
            *(float4*)bb = *(const float4*)&bhid[l * 128 + wv * 64 + lm * 4];
            #pragma unroll
            for (int r = 0; r < 4; ++r) {
                const int p = lq * 4 + r;
                float h[4][4];   // [j][state]
                #pragma unroll
                for (int j = 0; j < 4; ++j) {
                    const float zv  = acc[0][j][r] + bb[j];
                    const float zx  = acc[1][j][r];
                    const float zt  = acc[2][j][r];
                    const float zxx = acc[3][j][r];
                    const float y = fast_tanh(zv);
                    const float d = fmaf(-y, y, 1.f);
                    const float m = d * zx;
                    h[j][0] = y;
                    h[j][1] = m;
                    h[j][2] = d * zt;
                    h[j][3] = fmaf(d, zxx, -2.f * (y * m) * zx);
                }
                #pragma unroll
                for (int s = 0; s < 4; ++s) {
                    uint2 w;
                    w.x = pkf16(h[0][s], h[1][s]);
                    w.y = pkf16(h[2][s], h[3][s]);
                    *(uint2*)&Hh[(s * 16 + p) * HR + wc] = w;
                }
            }
            pb0 += 16384; pb1 += 16384; pb2 += 16384; pb3 += 16384;
            __syncthreads();   // H ready for next layer
        }
    } else {
        // ================= value-only path =================
        for (int l = 0; l < 7; ++l) {
            f32x4 acc[4][4];   // [m-tile][nt j]
            #pragma unroll
            for (int mt = 0; mt < 4; ++mt)
                #pragma unroll
                for (int j = 0; j < 4; ++j) acc[mt][j] = (f32x4){0.f, 0.f, 0.f, 0.f};

            #pragma unroll
            for (int ks = 0; ks < 4; ++ks) {
                const int ro = ks * 16 + lq * 4;
                f16x8 ah[4];
                #pragma unroll
                for (int mt = 0; mt < 4; ++mt)
                    ah[mt] = *(const f16x8*)&Hh[(mt * 16 + lm) * HR + ro];
                const f16x8 b0 = *(const f16x8*)(pb0 + ks * 512);
                const f16x8 b1 = *(const f16x8*)(pb1 + ks * 512);
                const f16x8 b2 = *(const f16x8*)(pb2 + ks * 512);
                const f16x8 b3 = *(const f16x8*)(pb3 + ks * 512);
                #pragma unroll
                for (int mt = 0; mt < 4; ++mt) {
                    acc[mt][0] = MFMA(ah[mt], b0, acc[mt][0]);
                    acc[mt][1] = MFMA(ah[mt], b1, acc[mt][1]);
                    acc[mt][2] = MFMA(ah[mt], b2, acc[mt][2]);
                    acc[mt][3] = MFMA(ah[mt], b3, acc[mt][3]);
                }
            }
            __syncthreads();

            float bb[4];
            *(float4*)bb = *(const float4*)&bhid[l * 128 + wv * 64 + lm * 4];
            #pragma unroll
            for (int mt = 0; mt < 4; ++mt) {
                #pragma unroll
                for (int r = 0; r < 4; ++r) {
                    const int p = mt * 16 + lq * 4 + r;
                    float y[4];
                    #pragma unroll
                    for (int j = 0; j < 4; ++j)
                        y[j] = fast_tanh(acc[mt][j][r] + bb[j]);
                    uint2 w;
                    w.x = pkf16(y[0], y[1]);
                    w.y = pkf16(y[2], y[3]);
                    *(uint2*)&Hh[p * HR + wc] = w;
                }
            }
            pb0 += 16384; pb1 += 16384; pb2 += 16384; pb3 += 16384;
            __syncthreads();
        }
    }

    // ---- output layer: 64 dots of length 128 (two 64-channel halves) ----
    {
        const int st = tid & 63;
        const int ch = tid >> 6;
        const int cb = ch * 32;        // 32 dwords = 64 channels per half
        float part = 0.f;
        #pragma unroll
        for (int c8 = 0; c8 < 8; ++c8) {
            const f16x8 hv = *(const f16x8*)&Hh[st * HR + cb + c8 * 4];
            const float4 w1 = *(const float4*)&Wout[ch * 64 + c8 * 8];
            const float4 w2 = *(const float4*)&Wout[ch * 64 + c8 * 8 + 4];
            part = fmaf((float)hv[0], w1.x, part);
            part = fmaf((float)hv[1], w1.y, part);
            part = fmaf((float)hv[2], w1.z, part);
            part = fmaf((float)hv[3], w1.w, part);
            part = fmaf((float)hv[4], w2.x, part);
            part = fmaf((float)hv[5], w2.y, part);
            part = fmaf((float)hv[6], w2.z, part);
            part = fmaf((float)hv[7], w2.w, part);
        }
        pbuf[ch * 64 + st] = part;
    }
    __syncthreads();
    if (tid < 64) dots[tid] = pbuf[tid] + pbuf[64 + tid];
    __syncthreads();
    if (!isv) {
        if (tid < 16) {
            const float u = dots[tid] + bout[0];
            out[8192 + blk * 16 + tid] =
                dots[32 + tid] + u * dots[16 + tid] - NU_F * dots[48 + tid];
        }
    } else {
        if (tid < 64) out[(blk - 8192) * 64 + tid] = dots[tid] + bout[0];
    }
}

extern "C" void kernel_launch(void* const* d_in, const int* in_sizes, int n_in,
                              void* d_out, int out_size, void* d_ws, size_t ws_size,
                              hipStream_t stream) {
    (void)in_sizes; (void)n_in; (void)ws_size; (void)out_size;
    const float* xf   = (const float*)d_in[0];
    const float* x0   = (const float*)d_in[1];
    const float* xbl  = (const float*)d_in[2];
    const float* xbr  = (const float*)d_in[3];
    const float* Win  = (const float*)d_in[4];
    const float* bin  = (const float*)d_in[5];
    const float* Whid = (const float*)d_in[6];
    const float* bhid = (const float*)d_in[7];
    const float* Wout = (const float*)d_in[8];
    const float* bout = (const float*)d_in[9];
    float* out = (float*)d_out;

    _Float16* wcf = (_Float16*)d_ws;   // 7*128*128 f16 = 224 KiB

    hipLaunchKernelGGL(prep_wfrag, dim3(114688 / 256), dim3(256), 0, stream,
                       Whid, wcf);
    hipLaunchKernelGGL(pinn_fused, dim3(8192 + 128), dim3(128), 0, stream,
                       xf, x0, xbl, xbr, Win, bin, bhid, Wout, bout, wcf, out);
}

// Round 12
// 218.151 us; speedup vs baseline: 1.0967x; 1.0967x over previous
//
#include <hip/hip_runtime.h>
#include <math.h>

#define NU_F 0.0031830988618379067f

typedef _Float16 f16x8 __attribute__((ext_vector_type(8)));
typedef float    f32x4 __attribute__((ext_vector_type(4)));

// tanh(z) = 1 - 2/(exp2(z*2log2e)+1); 5 VALU (2 transcendental)
__device__ __forceinline__ float fast_tanh(float z) {
    float e = __builtin_amdgcn_exp2f(2.885390082f * z);
    float r = __builtin_amdgcn_rcpf(e + 1.0f);
    return fmaf(-2.0f, r, 1.0f);
}

// pack two f32 -> f16x2 in one u32 (v_cvt_pkrtz_f32_f16), low16 = a
__device__ __forceinline__ unsigned pkf16(float a, float b) {
    auto v = __builtin_amdgcn_cvt_pkrtz(a, b);   // __fp16 ext_vector(2)
    return __builtin_bit_cast(unsigned, v);
}

// ---------------------------------------------------------------------------
// Prep: W_hid fp32 [7][128(k)][128(c)] -> single f16 (RNE) B-fragments,
// fragment-major (each wave-load = one coalesced 1 KiB block):
//   fid = (l*8 + nt)*4 + ks ; element = fid*512 + lane*8 + jj
//   k = ks*32 + q*8 + jj, lane = q*16 + nn
//   channel-QUAD map: nt = ((c>>6)<<2)|(c&3), nn = (c>>2)&15
//     -> real c = wv*64 + nn*4 + j   (wave wv: nt = wv*4+j)
// ---------------------------------------------------------------------------
__global__ void prep_wfrag(const float* __restrict__ Whid, _Float16* __restrict__ wcf)
{
    int t = blockIdx.x * 256 + threadIdx.x;   // 0 .. 114687
    const int l = t >> 14;
    const int r = t & 16383;
    const int k = r >> 7;
    const int c = r & 127;
    const _Float16 hi = (_Float16)Whid[t];
    const int ks = k >> 5, q = (k >> 3) & 3, jj = k & 7;
    const int nt = ((c >> 6) << 2) | (c & 3);
    const int nn = (c >> 2) & 15;
    const int lane = q * 16 + nn;
    wcf[((l * 8 + nt) * 4 + ks) * 512 + lane * 8 + jj] = hi;
}

#define HR 68
#define MFMA(A, B, C) __builtin_amdgcn_mfma_f32_16x16x32_f16((A), (B), (C), 0, 0, 0)

// ---------------------------------------------------------------------------
// Fused kernel, 128 thr = 2 waves; wave wv covers N-tiles wv*4..wv*4+3
// (channels wv*64 + nn*4 + j). Blocks 0..8191: 16 deriv pts (M rows =
// s*16+p, jet states v,vx,vt,vxx). Blocks 8192..8319: 64 value pts.
// H: SINGLE f16 buffer (u32-packed channel pairs), 64 x 68 dwords.
// __launch_bounds__(128,3): 170-reg unified cap. (128,4)'s 128-reg cap
// forced acc->AGPR(64) + arch capped at 64 -> 116 MB/dispatch scratch
// spills (round 11). 64 acc + ~100 arch fits in 170.
// ---------------------------------------------------------------------------
__global__ __launch_bounds__(128, 3)
void pinn_fused(const float* __restrict__ xf,
                const float* __restrict__ x0,  const float* __restrict__ xbl,
                const float* __restrict__ xbr,
                const float* __restrict__ Win,  const float* __restrict__ bin,
                const float* __restrict__ bhid,
                const float* __restrict__ Wout, const float* __restrict__ bout,
                const _Float16* __restrict__ wcf,
                float* __restrict__ out)
{
    __shared__ unsigned Hh[64 * HR];
    __shared__ float xpt[128];
    __shared__ float pbuf[128];
    __shared__ float dots[64];

    const int tid  = threadIdx.x;
    const int lane = tid & 63;
    const int wv   = tid >> 6;         // wave 0/1 -> N-tiles wv*4..wv*4+3
    const int lm   = lane & 15;
    const int lq   = lane >> 4;
    const int blk  = blockIdx.x;
    const bool isv = (blk >= 8192);

    if (!isv) {
        if (tid < 32) xpt[tid] = xf[blk * 32 + tid];
    } else {
        const int vb = blk - 8192;
        const float* src = (vb < 64) ? (x0 + vb * 128)
                         : (vb < 96) ? (xbl + (vb - 64) * 128)
                                     : (xbr + (vb - 96) * 128);
        xpt[tid] = src[tid];
    }
    __syncthreads();

    // ---- input layer: thread owns channel pair c0=2*(tid&63) ----
    const int cp = tid & 63;
    {
        const float2 w01 = *(const float2*)&Win[cp * 2];
        const float2 w11 = *(const float2*)&Win[128 + cp * 2];
        const float2 bb  = *(const float2*)&bin[cp * 2];
        if (!isv) {
            const int p0 = (tid >> 6) * 8;
            #pragma unroll
            for (int i = 0; i < 8; ++i) {
                const int p = p0 + i;
                const float x = xpt[2 * p], tt = xpt[2 * p + 1];
                const float za = fmaf(x, w01.x, fmaf(tt, w11.x, bb.x));
                const float zb = fmaf(x, w01.y, fmaf(tt, w11.y, bb.y));
                const float ya = fast_tanh(za), yb = fast_tanh(zb);
                const float da = 1.f - ya * ya, db = 1.f - yb * yb;
                Hh[(0 * 16 + p) * HR + cp] = pkf16(ya, yb);
                Hh[(1 * 16 + p) * HR + cp] = pkf16(da * w01.x, db * w01.y);
                Hh[(2 * 16 + p) * HR + cp] = pkf16(da * w11.x, db * w11.y);
                Hh[(3 * 16 + p) * HR + cp] =
                    pkf16(-2.f * ya * da * w01.x * w01.x,
                          -2.f * yb * db * w01.y * w01.y);
            }
        } else {
            const int p0 = (tid >> 6) * 32;
            #pragma unroll
            for (int i = 0; i < 32; ++i) {
                const int p = p0 + i;
                const float x = xpt[2 * p], tt = xpt[2 * p + 1];
                const float za = fmaf(x, w01.x, fmaf(tt, w11.x, bb.x));
                const float zb = fmaf(x, w01.y, fmaf(tt, w11.y, bb.y));
                Hh[p * HR + cp] = pkf16(fast_tanh(za), fast_tanh(zb));
            }
        }
    }
    __syncthreads();

    // B-fragment pointers: 4 N-tiles per wave, coalesced 1 KiB fragments.
    const _Float16* pb0 = wcf + (wv * 4 + 0) * 2048 + lane * 8;
    const _Float16* pb1 = wcf + (wv * 4 + 1) * 2048 + lane * 8;
    const _Float16* pb2 = wcf + (wv * 4 + 2) * 2048 + lane * 8;
    const _Float16* pb3 = wcf + (wv * 4 + 3) * 2048 + lane * 8;
    const int wc = wv * 32 + lm * 2;   // epilogue dword column (chan quad)

    if (!isv) {
        // ================= derivative path =================
        for (int l = 0; l < 7; ++l) {
            f32x4 acc[4][4];   // [state][nt j]
            #pragma unroll
            for (int s = 0; s < 4; ++s)
                #pragma unroll
                for (int j = 0; j < 4; ++j) acc[s][j] = (f32x4){0.f, 0.f, 0.f, 0.f};

            #pragma unroll
            for (int ks = 0; ks < 4; ++ks) {
                const int ro = ks * 16 + lq * 4;
                const f16x8 ah0 = *(const f16x8*)&Hh[(0 * 16 + lm) * HR + ro];
                const f16x8 ah1 = *(const f16x8*)&Hh[(1 * 16 + lm) * HR + ro];
                const f16x8 ah2 = *(const f16x8*)&Hh[(2 * 16 + lm) * HR + ro];
                const f16x8 ah3 = *(const f16x8*)&Hh[(3 * 16 + lm) * HR + ro];
                const f16x8 b0 = *(const f16x8*)(pb0 + ks * 512);
                const f16x8 b1 = *(const f16x8*)(pb1 + ks * 512);
                const f16x8 b2 = *(const f16x8*)(pb2 + ks * 512);
                const f16x8 b3 = *(const f16x8*)(pb3 + ks * 512);
                acc[0][0] = MFMA(ah0, b0, acc[0][0]);
                acc[1][0] = MFMA(ah1, b0, acc[1][0]);
                acc[2][0] = MFMA(ah2, b0, acc[2][0]);
                acc[3][0] = MFMA(ah3, b0, acc[3][0]);
                acc[0][1] = MFMA(ah0, b1, acc[0][1]);
                acc[1][1] = MFMA(ah1, b1, acc[1][1]);
                acc[2][1] = MFMA(ah2, b1, acc[2][1]);
                acc[3][1] = MFMA(ah3, b1, acc[3][1]);
                acc[0][2] = MFMA(ah0, b2, acc[0][2]);
                acc[1][2] = MFMA(ah1, b2, acc[1][2]);
                acc[2][2] = MFMA(ah2, b2, acc[2][2]);
                acc[3][2] = MFMA(ah3, b2, acc[3][2]);
                acc[0][3] = MFMA(ah0, b3, acc[0][3]);
                acc[1][3] = MFMA(ah1, b3, acc[1][3]);
                acc[2][3] = MFMA(ah2, b3, acc[2][3]);
                acc[3][3] = MFMA(ah3, b3, acc[3][3]);
            }
            __syncthreads();   // K-loop reads done before in-place overwrite

            float bb[4];
            *(float4*)bb = *(const float4*)&bhid[l * 128 + wv * 64 + lm * 4];
            #pragma unroll
            for (int r = 0; r < 4; ++r) {
                const int p = lq * 4 + r;
                float h[4][4];   // [j][state]
                #pragma unroll
                for (int j = 0; j < 4; ++j) {
                    const float zv  = acc[0][j][r] + bb[j];
                    const float zx  = acc[1][j][r];
                    const float zt  = acc[2][j][r];
                    const float zxx = acc[3][j][r];
                    const float y = fast_tanh(zv);
                    const float d = fmaf(-y, y, 1.f);
                    const float m = d * zx;
                    h[j][0] = y;
                    h[j][1] = m;
                    h[j][2] = d * zt;
                    h[j][3] = fmaf(d, zxx, -2.f * (y * m) * zx);
                }
                #pragma unroll
                for (int s = 0; s < 4; ++s) {
                    uint2 w;
                    w.x = pkf16(h[0][s], h[1][s]);
                    w.y = pkf16(h[2][s], h[3][s]);
                    *(uint2*)&Hh[(s * 16 + p) * HR + wc] = w;
                }
            }
            pb0 += 16384; pb1 += 16384; pb2 += 16384; pb3 += 16384;
            __syncthreads();   // H ready for next layer
        }
    } else {
        // ================= value-only path =================
        for (int l = 0; l < 7; ++l) {
            f32x4 acc[4][4];   // [m-tile][nt j]
            #pragma unroll
            for (int mt = 0; mt < 4; ++mt)
                #pragma unroll
                for (int j = 0; j < 4; ++j) acc[mt][j] = (f32x4){0.f, 0.f, 0.f, 0.f};

            #pragma unroll
            for (int ks = 0; ks < 4; ++ks) {
                const int ro = ks * 16 + lq * 4;
                f16x8 ah[4];
                #pragma unroll
                for (int mt = 0; mt < 4; ++mt)
                    ah[mt] = *(const f16x8*)&Hh[(mt * 16 + lm) * HR + ro];
                const f16x8 b0 = *(const f16x8*)(pb0 + ks * 512);
                const f16x8 b1 = *(const f16x8*)(pb1 + ks * 512);
                const f16x8 b2 = *(const f16x8*)(pb2 + ks * 512);
                const f16x8 b3 = *(const f16x8*)(pb3 + ks * 512);
                #pragma unroll
                for (int mt = 0; mt < 4; ++mt) {
                    acc[mt][0] = MFMA(ah[mt], b0, acc[mt][0]);
                    acc[mt][1] = MFMA(ah[mt], b1, acc[mt][1]);
                    acc[mt][2] = MFMA(ah[mt], b2, acc[mt][2]);
                    acc[mt][3] = MFMA(ah[mt], b3, acc[mt][3]);
                }
            }
            __syncthreads();

            float bb[4];
            *(float4*)bb = *(const float4*)&bhid[l * 128 + wv * 64 + lm * 4];
            #pragma unroll
            for (int mt = 0; mt < 4; ++mt) {
                #pragma unroll
                for (int r = 0; r < 4; ++r) {
                    const int p = mt * 16 + lq * 4 + r;
                    float y[4];
                    #pragma unroll
                    for (int j = 0; j < 4; ++j)
                        y[j] = fast_tanh(acc[mt][j][r] + bb[j]);
                    uint2 w;
                    w.x = pkf16(y[0], y[1]);
                    w.y = pkf16(y[2], y[3]);
                    *(uint2*)&Hh[p * HR + wc] = w;
                }
            }
            pb0 += 16384; pb1 += 16384; pb2 += 16384; pb3 += 16384;
            __syncthreads();
        }
    }

    // ---- output layer: 64 dots of length 128 (two 64-channel halves) ----
    {
        const int st = tid & 63;
        const int ch = tid >> 6;
        const int cb = ch * 32;        // 32 dwords = 64 channels per half
        float part = 0.f;
        #pragma unroll
        for (int c8 = 0; c8 < 8; ++c8) {
            const f16x8 hv = *(const f16x8*)&Hh[st * HR + cb + c8 * 4];
            const float4 w1 = *(const float4*)&Wout[ch * 64 + c8 * 8];
            const float4 w2 = *(const float4*)&Wout[ch * 64 + c8 * 8 + 4];
            part = fmaf((float)hv[0], w1.x, part);
            part = fmaf((float)hv[1], w1.y, part);
            part = fmaf((float)hv[2], w1.z, part);
            part = fmaf((float)hv[3], w1.w, part);
            part = fmaf((float)hv[4], w2.x, part);
            part = fmaf((float)hv[5], w2.y, part);
            part = fmaf((float)hv[6], w2.z, part);
            part = fmaf((float)hv[7], w2.w, part);
        }
        pbuf[ch * 64 + st] = part;
    }
    __syncthreads();
    if (tid < 64) dots[tid] = pbuf[tid] + pbuf[64 + tid];
    __syncthreads();
    if (!isv) {
        if (tid < 16) {
            const float u = dots[tid] + bout[0];
            out[8192 + blk * 16 + tid] =
                dots[32 + tid] + u * dots[16 + tid] - NU_F * dots[48 + tid];
        }
    } else {
        if (tid < 64) out[(blk - 8192) * 64 + tid] = dots[tid] + bout[0];
    }
}

extern "C" void kernel_launch(void* const* d_in, const int* in_sizes, int n_in,
                              void* d_out, int out_size, void* d_ws, size_t ws_size,
                              hipStream_t stream) {
    (void)in_sizes; (void)n_in; (void)ws_size; (void)out_size;
    const float* xf   = (const float*)d_in[0];
    const float* x0   = (const float*)d_in[1];
    const float* xbl  = (const float*)d_in[2];
    const float* xbr  = (const float*)d_in[3];
    const float* Win  = (const float*)d_in[4];
    const float* bin  = (const float*)d_in[5];
    const float* Whid = (const float*)d_in[6];
    const float* bhid = (const float*)d_in[7];
    const float* Wout = (const float*)d_in[8];
    const float* bout = (const float*)d_in[9];
    float* out = (float*)d_out;

    _Float16* wcf = (_Float16*)d_ws;   // 7*128*128 f16 = 224 KiB

    hipLaunchKernelGGL(prep_wfrag, dim3(114688 / 256), dim3(256), 0, stream,
                       Whid, wcf);
    hipLaunchKernelGGL(pinn_fused, dim3(8192 + 128), dim3(128), 0, stream,
                       xf, x0, xbl, xbr, Win, bin, bhid, Wout, bout, wcf, out);
}

// Round 13
// 212.266 us; speedup vs baseline: 1.1271x; 1.0277x over previous
//
#include <hip/hip_runtime.h>
#include <math.h>

#define NU_F 0.0031830988618379067f

typedef _Float16 f16x8 __attribute__((ext_vector_type(8)));
typedef float    f32x4 __attribute__((ext_vector_type(4)));

// tanh(z) = 1 - 2/(exp2(z*2log2e)+1); 5 VALU (2 transcendental)
__device__ __forceinline__ float fast_tanh(float z) {
    float e = __builtin_amdgcn_exp2f(2.885390082f * z);
    float r = __builtin_amdgcn_rcpf(e + 1.0f);
    return fmaf(-2.0f, r, 1.0f);
}

// pack two f32 -> f16x2 in one u32 (v_cvt_pkrtz_f32_f16), low16 = a
__device__ __forceinline__ unsigned pkf16(float a, float b) {
    auto v = __builtin_amdgcn_cvt_pkrtz(a, b);   // __fp16 ext_vector(2)
    return __builtin_bit_cast(unsigned, v);
}

// ---------------------------------------------------------------------------
// Prep v2 (gather-read, COALESCED-write): thread t owns dst dwords t*8..+7
// (one 16B f16x8 store/wave-lane -> fully coalesced). Source indices are
// recovered from the inverse fragment map and gathered from L2.
//   dst = fid*512 + lane*8 + jj ; fid = (l*8+nt)*4+ks ; lane = q*16+nn
//   k = ks*32 + q*8 + jj ; c = (nt>>2)*64 + nn*4 + (nt&3)
// (channel-QUAD map: real c = wv*64 + nn*4 + j for wave wv, nt = wv*4+j)
// Round-12 prep did scattered 2B stores -> ~55 us; this is the fix.
// ---------------------------------------------------------------------------
__global__ void prep_wfrag(const float* __restrict__ Whid, _Float16* __restrict__ wcf)
{
    const int t    = blockIdx.x * 256 + threadIdx.x;   // 0 .. 14335
    const int lane = t & 63;
    const int fid  = t >> 6;          // (l*8 + nt)*4 + ks, 0..223
    const int ks = fid & 3;
    const int nt = (fid >> 2) & 7;
    const int l  = fid >> 5;
    const int q  = lane >> 4;
    const int nn = lane & 15;
    const int c  = ((nt >> 2) << 6) + nn * 4 + (nt & 3);
    const int k0 = ks * 32 + q * 8;
    const float* src = Whid + l * 16384 + k0 * 128 + c;
    f16x8 v;
    #pragma unroll
    for (int jj = 0; jj < 8; ++jj)
        v[jj] = (_Float16)src[jj * 128];
    *(f16x8*)(wcf + (size_t)t * 8) = v;
}

#define HR 68
#define MFMA(A, B, C) __builtin_amdgcn_mfma_f32_16x16x32_f16((A), (B), (C), 0, 0, 0)

// ---------------------------------------------------------------------------
// Fused kernel, 128 thr = 2 waves; wave wv covers N-tiles wv*4..wv*4+3
// (channels wv*64 + nn*4 + j). Blocks 0..8191: 16 deriv pts (M rows =
// s*16+p, jet states v,vx,vt,vxx). Blocks 8192..8319: 64 value pts.
// H: SINGLE f16 buffer (u32-packed channel pairs), 64 x 68 dwords.
// __launch_bounds__(128,3): 170-reg unified cap. (128,4)'s 128-reg cap
// forced acc->AGPR(64) + arch capped at 64 -> 116 MB/dispatch scratch
// spills (round 11). 64 acc + ~100 arch fits in 170.
// ---------------------------------------------------------------------------
__global__ __launch_bounds__(128, 3)
void pinn_fused(const float* __restrict__ xf,
                const float* __restrict__ x0,  const float* __restrict__ xbl,
                const float* __restrict__ xbr,
                const float* __restrict__ Win,  const float* __restrict__ bin,
                const float* __restrict__ bhid,
                const float* __restrict__ Wout, const float* __restrict__ bout,
                const _Float16* __restrict__ wcf,
                float* __restrict__ out)
{
    __shared__ unsigned Hh[64 * HR];
    __shared__ float xpt[128];
    __shared__ float pbuf[128];
    __shared__ float dots[64];

    const int tid  = threadIdx.x;
    const int lane = tid & 63;
    const int wv   = tid >> 6;         // wave 0/1 -> N-tiles wv*4..wv*4+3
    const int lm   = lane & 15;
    const int lq   = lane >> 4;
    const int blk  = blockIdx.x;
    const bool isv = (blk >= 8192);

    if (!isv) {
        if (tid < 32) xpt[tid] = xf[blk * 32 + tid];
    } else {
        const int vb = blk - 8192;
        const float* src = (vb < 64) ? (x0 + vb * 128)
                         : (vb < 96) ? (xbl + (vb - 64) * 128)
                                     : (xbr + (vb - 96) * 128);
        xpt[tid] = src[tid];
    }
    __syncthreads();

    // ---- input layer: thread owns channel pair c0=2*(tid&63) ----
    const int cp = tid & 63;
    {
        const float2 w01 = *(const float2*)&Win[cp * 2];
        const float2 w11 = *(const float2*)&Win[128 + cp * 2];
        const float2 bb  = *(const float2*)&bin[cp * 2];
        if (!isv) {
            const int p0 = (tid >> 6) * 8;
            #pragma unroll
            for (int i = 0; i < 8; ++i) {
                const int p = p0 + i;
                const float x = xpt[2 * p], tt = xpt[2 * p + 1];
                const float za = fmaf(x, w01.x, fmaf(tt, w11.x, bb.x));
                const float zb = fmaf(x, w01.y, fmaf(tt, w11.y, bb.y));
                const float ya = fast_tanh(za), yb = fast_tanh(zb);
                const float da = 1.f - ya * ya, db = 1.f - yb * yb;
                Hh[(0 * 16 + p) * HR + cp] = pkf16(ya, yb);
                Hh[(1 * 16 + p) * HR + cp] = pkf16(da * w01.x, db * w01.y);
                Hh[(2 * 16 + p) * HR + cp] = pkf16(da * w11.x, db * w11.y);
                Hh[(3 * 16 + p) * HR + cp] =
                    pkf16(-2.f * ya * da * w01.x * w01.x,
                          -2.f * yb * db * w01.y * w01.y);
            }
        } else {
            const int p0 = (tid >> 6) * 32;
            #pragma unroll
            for (int i = 0; i < 32; ++i) {
                const int p = p0 + i;
                const float x = xpt[2 * p], tt = xpt[2 * p + 1];
                const float za = fmaf(x, w01.x, fmaf(tt, w11.x, bb.x));
                const float zb = fmaf(x, w01.y, fmaf(tt, w11.y, bb.y));
                Hh[p * HR + cp] = pkf16(fast_tanh(za), fast_tanh(zb));
            }
        }
    }
    __syncthreads();

    // B-fragment pointers: 4 N-tiles per wave, coalesced 1 KiB fragments.
    const _Float16* pb0 = wcf + (wv * 4 + 0) * 2048 + lane * 8;
    const _Float16* pb1 = wcf + (wv * 4 + 1) * 2048 + lane * 8;
    const _Float16* pb2 = wcf + (wv * 4 + 2) * 2048 + lane * 8;
    const _Float16* pb3 = wcf + (wv * 4 + 3) * 2048 + lane * 8;
    const int wc = wv * 32 + lm * 2;   // epilogue dword column (chan quad)

    if (!isv) {
        // ================= derivative path =================
        for (int l = 0; l < 7; ++l) {
            f32x4 acc[4][4];   // [state][nt j]
            #pragma unroll
            for (int s = 0; s < 4; ++s)
                #pragma unroll
                for (int j = 0; j < 4; ++j) acc[s][j] = (f32x4){0.f, 0.f, 0.f, 0.f};

            #pragma unroll
            for (int ks = 0; ks < 4; ++ks) {
                const int ro = ks * 16 + lq * 4;
                const f16x8 ah0 = *(const f16x8*)&Hh[(0 * 16 + lm) * HR + ro];
                const f16x8 ah1 = *(const f16x8*)&Hh[(1 * 16 + lm) * HR + ro];
                const f16x8 ah2 = *(const f16x8*)&Hh[(2 * 16 + lm) * HR + ro];
                const f16x8 ah3 = *(const f16x8*)&Hh[(3 * 16 + lm) * HR + ro];
                const f16x8 b0 = *(const f16x8*)(pb0 + ks * 512);
                const f16x8 b1 = *(const f16x8*)(pb1 + ks * 512);
                const f16x8 b2 = *(const f16x8*)(pb2 + ks * 512);
                const f16x8 b3 = *(const f16x8*)(pb3 + ks * 512);
                acc[0][0] = MFMA(ah0, b0, acc[0][0]);
                acc[1][0] = MFMA(ah1, b0, acc[1][0]);
                acc[2][0] = MFMA(ah2, b0, acc[2][0]);
                acc[3][0] = MFMA(ah3, b0, acc[3][0]);
                acc[0][1] = MFMA(ah0, b1, acc[0][1]);
                acc[1][1] = MFMA(ah1, b1, acc[1][1]);
                acc[2][1] = MFMA(ah2, b1, acc[2][1]);
                acc[3][1] = MFMA(ah3, b1, acc[3][1]);
                acc[0][2] = MFMA(ah0, b2, acc[0][2]);
                acc[1][2] = MFMA(ah1, b2, acc[1][2]);
                acc[2][2] = MFMA(ah2, b2, acc[2][2]);
                acc[3][2] = MFMA(ah3, b2, acc[3][2]);
                acc[0][3] = MFMA(ah0, b3, acc[0][3]);
                acc[1][3] = MFMA(ah1, b3, acc[1][3]);
                acc[2][3] = MFMA(ah2, b3, acc[2][3]);
                acc[3][3] = MFMA(ah3, b3, acc[3][3]);
            }
            __syncthreads();   // K-loop reads done before in-place overwrite

            float bb[4];
            *(float4*)bb = *(const float4*)&bhid[l * 128 + wv * 64 + lm * 4];
            #pragma unroll
            for (int r = 0; r < 4; ++r) {
                const int p = lq * 4 + r;
                float h[4][4];   // [j][state]
                #pragma unroll
                for (int j = 0; j < 4; ++j) {
                    const float zv  = acc[0][j][r] + bb[j];
                    const float zx  = acc[1][j][r];
                    const float zt  = acc[2][j][r];
                    const float zxx = acc[3][j][r];
                    const float y = fast_tanh(zv);
                    const float d = fmaf(-y, y, 1.f);
                    const float m = d * zx;
                    h[j][0] = y;
                    h[j][1] = m;
                    h[j][2] = d * zt;
                    h[j][3] = fmaf(d, zxx, -2.f * (y * m) * zx);
                }
                #pragma unroll
                for (int s = 0; s < 4; ++s) {
                    uint2 w;
                    w.x = pkf16(h[0][s], h[1][s]);
                    w.y = pkf16(h[2][s], h[3][s]);
                    *(uint2*)&Hh[(s * 16 + p) * HR + wc] = w;
                }
            }
            pb0 += 16384; pb1 += 16384; pb2 += 16384; pb3 += 16384;
            __syncthreads();   // H ready for next layer
        }
    } else {
        // ================= value-only path =================
        for (int l = 0; l < 7; ++l) {
            f32x4 acc[4][4];   // [m-tile][nt j]
            #pragma unroll
            for (int mt = 0; mt < 4; ++mt)
                #pragma unroll
                for (int j = 0; j < 4; ++j) acc[mt][j] = (f32x4){0.f, 0.f, 0.f, 0.f};

            #pragma unroll
            for (int ks = 0; ks < 4; ++ks) {
                const int ro = ks * 16 + lq * 4;
                f16x8 ah[4];
                #pragma unroll
                for (int mt = 0; mt < 4; ++mt)
                    ah[mt] = *(const f16x8*)&Hh[(mt * 16 + lm) * HR + ro];
                const f16x8 b0 = *(const f16x8*)(pb0 + ks * 512);
                const f16x8 b1 = *(const f16x8*)(pb1 + ks * 512);
                const f16x8 b2 = *(const f16x8*)(pb2 + ks * 512);
                const f16x8 b3 = *(const f16x8*)(pb3 + ks * 512);
                #pragma unroll
                for (int mt = 0; mt < 4; ++mt) {
                    acc[mt][0] = MFMA(ah[mt], b0, acc[mt][0]);
                    acc[mt][1] = MFMA(ah[mt], b1, acc[mt][1]);
                    acc[mt][2] = MFMA(ah[mt], b2, acc[mt][2]);
                    acc[mt][3] = MFMA(ah[mt], b3, acc[mt][3]);
                }
            }
            __syncthreads();

            float bb[4];
            *(float4*)bb = *(const float4*)&bhid[l * 128 + wv * 64 + lm * 4];
            #pragma unroll
            for (int mt = 0; mt < 4; ++mt) {
                #pragma unroll
                for (int r = 0; r < 4; ++r) {
                    const int p = mt * 16 + lq * 4 + r;
                    float y[4];
                    #pragma unroll
                    for (int j = 0; j < 4; ++j)
                        y[j] = fast_tanh(acc[mt][j][r] + bb[j]);
                    uint2 w;
                    w.x = pkf16(y[0], y[1]);
                    w.y = pkf16(y[2], y[3]);
                    *(uint2*)&Hh[p * HR + wc] = w;
                }
            }
            pb0 += 16384; pb1 += 16384; pb2 += 16384; pb3 += 16384;
            __syncthreads();
        }
    }

    // ---- output layer: 64 dots of length 128 (two 64-channel halves) ----
    {
        const int st = tid & 63;
        const int ch = tid >> 6;
        const int cb = ch * 32;        // 32 dwords = 64 channels per half
        float part = 0.f;
        #pragma unroll
        for (int c8 = 0; c8 < 8; ++c8) {
            const f16x8 hv = *(const f16x8*)&Hh[st * HR + cb + c8 * 4];
            const float4 w1 = *(const float4*)&Wout[ch * 64 + c8 * 8];
            const float4 w2 = *(const float4*)&Wout[ch * 64 + c8 * 8 + 4];
            part = fmaf((float)hv[0], w1.x, part);
            part = fmaf((float)hv[1], w1.y, part);
            part = fmaf((float)hv[2], w1.z, part);
            part = fmaf((float)hv[3], w1.w, part);
            part = fmaf((float)hv[4], w2.x, part);
            part = fmaf((float)hv[5], w2.y, part);
            part = fmaf((float)hv[6], w2.z, part);
            part = fmaf((float)hv[7], w2.w, part);
        }
        pbuf[ch * 64 + st] = part;
    }
    __syncthreads();
    if (tid < 64) dots[tid] = pbuf[tid] + pbuf[64 + tid];
    __syncthreads();
    if (!isv) {
        if (tid < 16) {
            const float u = dots[tid] + bout[0];
            out[8192 + blk * 16 + tid] =
                dots[32 + tid] + u * dots[16 + tid] - NU_F * dots[48 + tid];
        }
    } else {
        if (tid < 64) out[(blk - 8192) * 64 + tid] = dots[tid] + bout[0];
    }
}

extern "C" void kernel_launch(void* const* d_in, const int* in_sizes, int n_in,
                              void* d_out, int out_size, void* d_ws, size_t ws_size,
                              hipStream_t stream) {
    (void)in_sizes; (void)n_in; (void)ws_size; (void)out_size;
    const float* xf   = (const float*)d_in[0];
    const float* x0   = (const float*)d_in[1];
    const float* xbl  = (const float*)d_in[2];
    const float* xbr  = (const float*)d_in[3];
    const float* Win  = (const float*)d_in[4];
    const float* bin  = (const float*)d_in[5];
    const float* Whid = (const float*)d_in[6];
    const float* bhid = (const float*)d_in[7];
    const float* Wout = (const float*)d_in[8];
    const float* bout = (const float*)d_in[9];
    float* out = (float*)d_out;

    _Float16* wcf = (_Float16*)d_ws;   // 7*128*128 f16 = 224 KiB

    hipLaunchKernelGGL(prep_wfrag, dim3(14336 / 256), dim3(256), 0, stream,
                       Whid, wcf);
    hipLaunchKernelGGL(pinn_fused, dim3(8192 + 128), dim3(128), 0, stream,
                       xf, x0, xbl, xbr, Win, bin, bhid, Wout, bout, wcf, out);
}